// Round 1
// baseline (186.563 us; speedup 1.0000x reference)
//
#include <hip/hip_runtime.h>
#include <hip/hip_bf16.h>
#include <math.h>

#define B_SZ 16
#define L_SEQ 128
#define D_M 32
#define N_ST 8
#define R_DT 2
#define HW 65536           // 256*256
#define NROWS (B_SZ * 128) // 2048 rows for the max reduction

// Device-global scratch (avoids any dependence on ws_size).
__device__ float g_s[NROWS];                       // (16,128) maxima
__device__ float g_xz[B_SZ * 64 * L_SEQ];          // (16,64,128)
__device__ float g_outf[B_SZ * D_M * L_SEQ];       // forward branch out
__device__ float g_outb[B_SZ * D_M * L_SEQ];       // backward branch out (stored pre-flipped)

__device__ __forceinline__ float siluf(float x) {
    return x / (1.f + __expf(-x) * 0.f + expf(-x) * 1.f); // keep accurate expf
}
__device__ __forceinline__ float silu_acc(float x) {
    return x / (1.f + expf(-x));
}
__device__ __forceinline__ float softplusf(float x) {
    return (x > 20.f) ? x : log1pf(expf(x));
}

// ---------------- K1: s = max over H*W per (b,c) row ----------------
__global__ __launch_bounds__(256) void kmax(const float* __restrict__ x) {
    const int row = blockIdx.x;
    const float4* p = reinterpret_cast<const float4*>(x + (size_t)row * HW);
    float m = -INFINITY;
#pragma unroll 4
    for (int i = threadIdx.x; i < HW / 4; i += 256) {
        float4 v = p[i];
        m = fmaxf(m, fmaxf(fmaxf(v.x, v.y), fmaxf(v.z, v.w)));
    }
#pragma unroll
    for (int off = 32; off >= 1; off >>= 1)
        m = fmaxf(m, __shfl_xor(m, off));
    __shared__ float sm[4];
    if ((threadIdx.x & 63) == 0) sm[threadIdx.x >> 6] = m;
    __syncthreads();
    if (threadIdx.x == 0)
        g_s[row] = fmaxf(fmaxf(sm[0], sm[1]), fmaxf(sm[2], sm[3]));
}

// ---------------- K2: h = s*w1+b1 -> LN -> in_proj -> g_xz ----------------
__global__ __launch_bounds__(128) void kprelude(const float* __restrict__ w1,
                                                const float* __restrict__ b1,
                                                const float* __restrict__ ln_g,
                                                const float* __restrict__ ln_b,
                                                const float* __restrict__ Win) {
    const int b = blockIdx.x;
    const int l = threadIdx.x; // 0..127
    __shared__ float sW[64 * 32];
    for (int i = l; i < 64 * 32; i += 128) sW[i] = Win[i];
    __syncthreads();

    const float s = g_s[b * L_SEQ + l];
    float h[D_M];
    float mean = 0.f;
#pragma unroll
    for (int d = 0; d < D_M; d++) { h[d] = s * w1[d] + b1[d]; mean += h[d]; }
    mean *= (1.f / D_M);
    float var = 0.f;
#pragma unroll
    for (int d = 0; d < D_M; d++) { float t = h[d] - mean; var += t * t; }
    var *= (1.f / D_M);
    const float rs = rsqrtf(var + 1e-5f);
#pragma unroll
    for (int d = 0; d < D_M; d++) h[d] = (h[d] - mean) * rs * ln_g[d] + ln_b[d];

    for (int e = 0; e < 64; e++) {
        float acc = 0.f;
#pragma unroll
        for (int d = 0; d < D_M; d++) acc += h[d] * sW[e * 32 + d];
        g_xz[(b * 64 + e) * L_SEQ + l] = acc;
    }
}

// ---------------- K3: one block per (batch, direction) ----------------
__global__ __launch_bounds__(256) void kbranch(
    const float* __restrict__ cw_f, const float* __restrict__ cb_f,
    const float* __restrict__ xp_f, const float* __restrict__ dtw_f,
    const float* __restrict__ dtb_f, const float* __restrict__ Al_f,
    const float* __restrict__ Dp_f,
    const float* __restrict__ cw_b, const float* __restrict__ cb_b,
    const float* __restrict__ xp_b, const float* __restrict__ dtw_b,
    const float* __restrict__ dtb_b, const float* __restrict__ Al_b,
    const float* __restrict__ Dp_b) {
    const int b = blockIdx.x >> 1;
    const int beta = blockIdx.x & 1;
    const int tid = threadIdx.x;

    const float* cw  = beta ? cw_b  : cw_f;
    const float* cb  = beta ? cb_b  : cb_f;
    const float* xp  = beta ? xp_b  : xp_f;
    const float* dtw = beta ? dtw_b : dtw_f;
    const float* dtb = beta ? dtb_b : dtb_f;
    const float* Al  = beta ? Al_b  : Al_f;
    const float* Dp  = beta ? Dp_b  : Dp_f;
    float* outp = beta ? g_outb : g_outf;

    __shared__ float sx[D_M * L_SEQ];      // x half; reused as delta[l*32+d]
    __shared__ float su[D_M * 129];        // padded to kill bank conflicts
    __shared__ float sy[D_M * L_SEQ];
    __shared__ float sdt[L_SEQ * 2];
    __shared__ float sB[L_SEQ * N_ST];
    __shared__ float sC[L_SEQ * N_ST];
    __shared__ float sxp[18 * 32];

    // load x half (with flip for backward branch)
    for (int i = tid; i < D_M * L_SEQ; i += 256) {
        const int d = i >> 7, l = i & 127;
        const int gl = beta ? (127 - l) : l;
        sx[d * 128 + l] = g_xz[(b * 64 + d) * L_SEQ + gl];
    }
    for (int i = tid; i < 18 * 32; i += 256) sxp[i] = xp[i];
    __syncthreads();

    // causal depthwise conv(4) + SiLU
    for (int i = tid; i < D_M * L_SEQ; i += 256) {
        const int d = i >> 7, l = i & 127;
        float acc = cb[d];
#pragma unroll
        for (int k = 0; k < 4; k++) {
            const int j = l - 3 + k;
            if (j >= 0) acc += cw[d * 4 + k] * sx[d * 128 + j];
        }
        su[d * 129 + l] = silu_acc(acc);
    }
    __syncthreads();

    // x_dbl = u^T * xproj_w^T : (l, r) with r in [0,18)
    for (int i = tid; i < L_SEQ * 18; i += 256) {
        const int l = i / 18, r = i - l * 18;
        float acc = 0.f;
#pragma unroll
        for (int d = 0; d < D_M; d++) acc += su[d * 129 + l] * sxp[r * 32 + d];
        if (r < 2)       sdt[l * 2 + r] = acc;
        else if (r < 10) sB[l * 8 + (r - 2)] = acc;
        else             sC[l * 8 + (r - 10)] = acc;
    }
    __syncthreads();

    // delta[l][d] = softplus(dt @ dtproj_w^T + dtproj_b) ; overwrite sx
    float* sdelta = sx;
    for (int i = tid; i < L_SEQ * D_M; i += 256) {
        const int l = i >> 5, d = i & 31;
        const float t = sdt[l * 2 + 0] * dtw[d * 2 + 0] +
                        sdt[l * 2 + 1] * dtw[d * 2 + 1] + dtb[d];
        sdelta[l * 32 + d] = softplusf(t);
    }
    __syncthreads();

    // sequential SSM scan: thread = (d, n)
    {
        const int d = tid >> 3, n = tid & 7;
        const float A = -expf(Al[d * 8 + n]);
        const float Dd = Dp[d];
        float hst = 0.f;
        for (int l = 0; l < L_SEQ; l++) {
            const float dl = sdelta[l * 32 + d];
            const float ul = su[d * 129 + l];
            const float dA = expf(dl * A);
            hst = dA * hst + (dl * ul) * sB[l * 8 + n];
            float y = hst * sC[l * 8 + n];
            y += __shfl_xor(y, 1, 8);
            y += __shfl_xor(y, 2, 8);
            y += __shfl_xor(y, 4, 8);
            if (n == 0) sy[d * 128 + l] = y + Dd * ul;
        }
    }
    __syncthreads();

    // out = y * silu(z); backward branch stored pre-flipped
    for (int i = tid; i < D_M * L_SEQ; i += 256) {
        const int d = i >> 7, l = i & 127;
        const int gl = beta ? (127 - l) : l;
        const float z = g_xz[(b * 64 + 32 + d) * L_SEQ + gl];
        outp[(b * D_M + d) * L_SEQ + gl] = sy[d * 128 + l] * silu_acc(z);
    }
}

// ---------------- K4: combine, LN/2, out_proj, w2, sigmoid ----------------
__global__ __launch_bounds__(128) void kfinal(const float* __restrict__ ng,
                                              const float* __restrict__ nb,
                                              const float* __restrict__ Wout,
                                              const float* __restrict__ w2,
                                              const float* __restrict__ b2,
                                              float* __restrict__ out) {
    const int b = blockIdx.x;
    const int l = threadIdx.x;
    __shared__ float sW[32 * 32];
    for (int i = l; i < 32 * 32; i += 128) sW[i] = Wout[i];
    __syncthreads();

    float v[D_M];
    float mean = 0.f;
#pragma unroll
    for (int d = 0; d < D_M; d++) {
        v[d] = g_outf[(b * D_M + d) * L_SEQ + l] + g_outb[(b * D_M + d) * L_SEQ + l];
        mean += v[d];
    }
    mean *= (1.f / D_M);
    float var = 0.f;
#pragma unroll
    for (int d = 0; d < D_M; d++) { float t = v[d] - mean; var += t * t; }
    var *= (1.f / D_M);
    const float rs = rsqrtf(var + 1e-5f);
#pragma unroll
    for (int d = 0; d < D_M; d++)
        v[d] = ((v[d] - mean) * rs * ng[d] + nb[d]) * 0.5f;

    float acc = 0.f;
    for (int o = 0; o < D_M; o++) {
        float t = 0.f;
#pragma unroll
        for (int d = 0; d < D_M; d++) t += v[d] * sW[o * 32 + d];
        acc += t * w2[o];
    }
    acc += b2[0];
    out[b * L_SEQ + l] = 1.f / (1.f + expf(-acc));
}

extern "C" void kernel_launch(void* const* d_in, const int* in_sizes, int n_in,
                              void* d_out, int out_size, void* d_ws, size_t ws_size,
                              hipStream_t stream) {
    const float* x        = (const float*)d_in[0];
    const float* w1       = (const float*)d_in[1];
    const float* b1       = (const float*)d_in[2];
    const float* ln_g     = (const float*)d_in[3];
    const float* ln_b     = (const float*)d_in[4];
    const float* in_proj  = (const float*)d_in[5];
    const float* cw_f     = (const float*)d_in[6];
    const float* cb_f     = (const float*)d_in[7];
    const float* xp_f     = (const float*)d_in[8];
    const float* dtw_f    = (const float*)d_in[9];
    const float* dtb_f    = (const float*)d_in[10];
    const float* Al_f     = (const float*)d_in[11];
    const float* Dp_f     = (const float*)d_in[12];
    const float* cw_b     = (const float*)d_in[13];
    const float* cb_b     = (const float*)d_in[14];
    const float* xp_b     = (const float*)d_in[15];
    const float* dtw_b    = (const float*)d_in[16];
    const float* dtb_b    = (const float*)d_in[17];
    const float* Al_b     = (const float*)d_in[18];
    const float* Dp_b     = (const float*)d_in[19];
    const float* norm_g   = (const float*)d_in[20];
    const float* norm_b   = (const float*)d_in[21];
    const float* Wout     = (const float*)d_in[22];
    const float* w2       = (const float*)d_in[23];
    const float* b2       = (const float*)d_in[24];

    kmax<<<NROWS, 256, 0, stream>>>(x);
    kprelude<<<B_SZ, 128, 0, stream>>>(w1, b1, ln_g, ln_b, in_proj);
    kbranch<<<B_SZ * 2, 256, 0, stream>>>(cw_f, cb_f, xp_f, dtw_f, dtb_f, Al_f, Dp_f,
                                          cw_b, cb_b, xp_b, dtw_b, dtb_b, Al_b, Dp_b);
    kfinal<<<B_SZ, 128, 0, stream>>>(norm_g, norm_b, Wout, w2, b2, (float*)d_out);
}

// Round 3
// 143.727 us; speedup vs baseline: 1.2980x; 1.2980x over previous
//
#include <hip/hip_runtime.h>
#include <hip/hip_bf16.h>
#include <math.h>

#define B_SZ 16
#define L_SEQ 128
#define D_M 32
#define N_ST 8
#define HW 65536           // 256*256
#define NROWS (B_SZ * 128) // 2048 (b,c) rows
#define NCHUNK 2           // chunks per row for kmax

typedef float vfloat4 __attribute__((ext_vector_type(4)));

// Device-global scratch
__device__ float g_part[NROWS * NCHUNK];       // partial maxima
__device__ float g_y0[B_SZ * D_M * L_SEQ];     // forward branch y (incl. D*u), fwd orientation
__device__ float g_y1[B_SZ * D_M * L_SEQ];     // backward branch y, already flipped back

__device__ __forceinline__ float silu_acc(float x) {
    return x / (1.f + expf(-x));
}
__device__ __forceinline__ float softplusf(float x) {
    return (x > 20.f) ? x : log1pf(expf(x));
}

// ---------------- K1: partial max over half-rows ----------------
__global__ __launch_bounds__(256) void kmax(const float* __restrict__ x) {
    const int blk = blockIdx.x;                 // 0..4095
    const vfloat4* __restrict__ p =
        reinterpret_cast<const vfloat4*>(x) + (size_t)blk * 8192;
    const int t = threadIdx.x;
    float m0 = -INFINITY, m1 = -INFINITY, m2 = -INFINITY, m3 = -INFINITY;
#pragma unroll
    for (int i = 0; i < 8192; i += 1024) {
        vfloat4 v0 = __builtin_nontemporal_load(p + i + t);
        vfloat4 v1 = __builtin_nontemporal_load(p + i + t + 256);
        vfloat4 v2 = __builtin_nontemporal_load(p + i + t + 512);
        vfloat4 v3 = __builtin_nontemporal_load(p + i + t + 768);
        m0 = fmaxf(m0, fmaxf(fmaxf(v0.x, v0.y), fmaxf(v0.z, v0.w)));
        m1 = fmaxf(m1, fmaxf(fmaxf(v1.x, v1.y), fmaxf(v1.z, v1.w)));
        m2 = fmaxf(m2, fmaxf(fmaxf(v2.x, v2.y), fmaxf(v2.z, v2.w)));
        m3 = fmaxf(m3, fmaxf(fmaxf(v3.x, v3.y), fmaxf(v3.z, v3.w)));
    }
    float m = fmaxf(fmaxf(m0, m1), fmaxf(m2, m3));
#pragma unroll
    for (int off = 32; off >= 1; off >>= 1)
        m = fmaxf(m, __shfl_xor(m, off));
    __shared__ float sm[4];
    if ((threadIdx.x & 63) == 0) sm[threadIdx.x >> 6] = m;
    __syncthreads();
    if (threadIdx.x == 0)
        g_part[blk] = fmaxf(fmaxf(sm[0], sm[1]), fmaxf(sm[2], sm[3]));
}

// ---------------- K2: per (batch, direction): prelude + conv + SSM scan ----------------
__global__ __launch_bounds__(256) void kbranch(
    const float* __restrict__ w1,  const float* __restrict__ b1,
    const float* __restrict__ lng, const float* __restrict__ lnb,
    const float* __restrict__ Win,
    const float* __restrict__ cw_f, const float* __restrict__ cb_f,
    const float* __restrict__ xp_f, const float* __restrict__ dtw_f,
    const float* __restrict__ dtb_f, const float* __restrict__ Al_f,
    const float* __restrict__ Dp_f,
    const float* __restrict__ cw_b, const float* __restrict__ cb_b,
    const float* __restrict__ xp_b, const float* __restrict__ dtw_b,
    const float* __restrict__ dtb_b, const float* __restrict__ Al_b,
    const float* __restrict__ Dp_b) {
    const int b = blockIdx.x >> 1;
    const int beta = blockIdx.x & 1;
    const int tid = threadIdx.x;

    const float* cw  = beta ? cw_b  : cw_f;
    const float* cb  = beta ? cb_b  : cb_f;
    const float* xp  = beta ? xp_b  : xp_f;
    const float* dtw = beta ? dtw_b : dtw_f;
    const float* dtb = beta ? dtb_b : dtb_f;
    const float* Al  = beta ? Al_b  : Al_f;
    const float* Dp  = beta ? Dp_b  : Dp_f;
    float* yout = beta ? g_y1 : g_y0;

    // Manually-overlaid LDS (62 KB)
    __shared__ float S[15520];
    float* sh  = S;                 // [128][33]  h         (phase 1-2) = 4224
    float* sy  = S;                 // [32][128]  y         (scan+)     = 4096  (overlays sh)
    float* sWx = S + 4224;          // [32][32]   Win x-half(phase 2)   = 1024
    float* sxp = S + 4224;          // [18][33]   xproj pad (phase 4)   = 594   (overlays sWx)
    float* sdt = S + 4224 + 594;    // [128][2]   dt        (phase 4-5) = 256
    float* sx  = S + 5248;          // [32][128]  x         (conv)      = 4096
    float* sdl = S + 5248;          // [128][32]  delta     (scan)      = 4096  (overlays sx)
    float* su  = S + 9344;          // [32][129]  u         (conv->end) = 4128
    float* sB  = S + 13472;         // [128][8]                          = 1024
    float* sC  = S + 14496;         // [128][8]                          = 1024

    // Phase 1: h = LN(s*w1+b1); also stage Win x-half
    for (int i = tid; i < 1024; i += 256) sWx[i] = Win[i];
    if (tid < 128) {
        const int l = tid;
        const int r2 = (b * L_SEQ + l) * NCHUNK;
        const float s = fmaxf(g_part[r2], g_part[r2 + 1]);
        float h[D_M];
        float mean = 0.f;
#pragma unroll
        for (int d = 0; d < D_M; d++) { h[d] = s * w1[d] + b1[d]; mean += h[d]; }
        mean *= (1.f / D_M);
        float var = 0.f;
#pragma unroll
        for (int d = 0; d < D_M; d++) { float t = h[d] - mean; var += t * t; }
        var *= (1.f / D_M);
        const float rs = rsqrtf(var + 1e-5f);
#pragma unroll
        for (int d = 0; d < D_M; d++)
            sh[l * 33 + d] = (h[d] - mean) * rs * lng[d] + lnb[d];
    }
    __syncthreads();

    // Phase 2: x-half GEMV, stored pre-flipped for backward branch
    for (int i = tid; i < 4096; i += 256) {
        const int e = i >> 7, l = i & 127;
        float acc = 0.f;
#pragma unroll
        for (int d = 0; d < D_M; d++) acc += sh[l * 33 + d] * sWx[e * 32 + d];
        sx[e * 128 + (beta ? 127 - l : l)] = acc;
    }
    __syncthreads();

    // Phase 3: causal depthwise conv(4) + SiLU; also stage padded xproj
    for (int i = tid; i < 576; i += 256) {
        const int r = i >> 5, d = i & 31;
        sxp[r * 33 + d] = xp[i];
    }
    for (int i = tid; i < 4096; i += 256) {
        const int d = i >> 7, l = i & 127;
        float acc = cb[d];
#pragma unroll
        for (int k = 0; k < 4; k++) {
            const int j = l - 3 + k;
            if (j >= 0) acc += cw[d * 4 + k] * sx[d * 128 + j];
        }
        su[d * 129 + l] = silu_acc(acc);
    }
    __syncthreads();

    // Phase 4: x_dbl = u^T @ xproj^T -> dt, B, C
    for (int i = tid; i < L_SEQ * 18; i += 256) {
        const int l = i / 18, r = i - l * 18;
        float acc = 0.f;
#pragma unroll
        for (int d = 0; d < D_M; d++) acc += su[d * 129 + l] * sxp[r * 33 + d];
        if (r < 2)       sdt[l * 2 + r] = acc;
        else if (r < 10) sB[l * 8 + (r - 2)] = acc;
        else             sC[l * 8 + (r - 10)] = acc;
    }
    __syncthreads();

    // Phase 5: delta = softplus(dt @ dtw^T + dtb)  (overwrites sx)
    for (int i = tid; i < L_SEQ * D_M; i += 256) {
        const int l = i >> 5, d = i & 31;
        const float t = sdt[l * 2 + 0] * dtw[d * 2 + 0] +
                        sdt[l * 2 + 1] * dtw[d * 2 + 1] + dtb[d];
        sdl[l * 32 + d] = softplusf(t);
    }
    __syncthreads();

    // Phase 6: sequential scan, thread = (d, n); sy overlays sh
    {
        const int d = tid >> 3, n = tid & 7;
        const float A = -expf(Al[d * 8 + n]);
        const float Dd = Dp[d];
        float hst = 0.f;
        for (int l = 0; l < L_SEQ; l++) {
            const float dl = sdl[l * 32 + d];
            const float ul = su[d * 129 + l];
            const float dA = expf(dl * A);
            hst = dA * hst + (dl * ul) * sB[l * 8 + n];
            float y = hst * sC[l * 8 + n];
            y += __shfl_xor(y, 1, 8);
            y += __shfl_xor(y, 2, 8);
            y += __shfl_xor(y, 4, 8);
            if (n == 0) sy[d * 128 + l] = y + Dd * ul;
        }
    }
    __syncthreads();

    // Phase 7: store y (backward branch flipped back to forward orientation)
    for (int i = tid; i < 4096; i += 256) {
        const int d = i >> 7, l = i & 127;
        const int gl = beta ? (127 - l) : l;
        yout[(b * D_M + d) * L_SEQ + gl] = sy[d * 128 + l];
    }
}

// ---------------- K3: z GEMV + combine + LN/2 + out_proj + w2 + sigmoid ----------------
__global__ __launch_bounds__(128) void kfinal(
    const float* __restrict__ w1,  const float* __restrict__ b1,
    const float* __restrict__ lng, const float* __restrict__ lnb,
    const float* __restrict__ Win,
    const float* __restrict__ ng,  const float* __restrict__ nb,
    const float* __restrict__ Wout, const float* __restrict__ w2,
    const float* __restrict__ b2,  float* __restrict__ out) {
    const int b = blockIdx.x;
    const int l = threadIdx.x;
    __shared__ float sWz[32 * 32];
    __shared__ float sWo[32 * 32];
    for (int i = l; i < 1024; i += 128) {
        sWz[i] = Win[1024 + i];   // z-half rows of in_proj
        sWo[i] = Wout[i];
    }
    __syncthreads();

    // prelude h (recomputed, trivial)
    const int r2 = (b * L_SEQ + l) * NCHUNK;
    const float s = fmaxf(g_part[r2], g_part[r2 + 1]);
    float h[D_M];
    float mean = 0.f;
#pragma unroll
    for (int d = 0; d < D_M; d++) { h[d] = s * w1[d] + b1[d]; mean += h[d]; }
    mean *= (1.f / D_M);
    float var = 0.f;
#pragma unroll
    for (int d = 0; d < D_M; d++) { float t = h[d] - mean; var += t * t; }
    var *= (1.f / D_M);
    float rs = rsqrtf(var + 1e-5f);
#pragma unroll
    for (int d = 0; d < D_M; d++) h[d] = (h[d] - mean) * rs * lng[d] + lnb[d];

    // v[d] = (y_f + y_b)[d][l] * silu(z[d][l]);  z = h @ Wz^T
    float v[D_M];
#pragma unroll
    for (int d = 0; d < D_M; d++) {
        float z = 0.f;
#pragma unroll
        for (int k = 0; k < D_M; k++) z += h[k] * sWz[d * 32 + k];
        const float yc = g_y0[(b * D_M + d) * L_SEQ + l] +
                         g_y1[(b * D_M + d) * L_SEQ + l];
        v[d] = yc * silu_acc(z);
    }

    // LN / 2
    mean = 0.f;
#pragma unroll
    for (int d = 0; d < D_M; d++) mean += v[d];
    mean *= (1.f / D_M);
    var = 0.f;
#pragma unroll
    for (int d = 0; d < D_M; d++) { float t = v[d] - mean; var += t * t; }
    var *= (1.f / D_M);
    rs = rsqrtf(var + 1e-5f);
#pragma unroll
    for (int d = 0; d < D_M; d++)
        v[d] = ((v[d] - mean) * rs * ng[d] + nb[d]) * 0.5f;

    // out_proj then w2 dot, sigmoid
    float acc = 0.f;
    for (int o = 0; o < D_M; o++) {
        float t = 0.f;
#pragma unroll
        for (int d = 0; d < D_M; d++) t += v[d] * sWo[o * 32 + d];
        acc += t * w2[o];
    }
    acc += b2[0];
    out[b * L_SEQ + l] = 1.f / (1.f + expf(-acc));
}

extern "C" void kernel_launch(void* const* d_in, const int* in_sizes, int n_in,
                              void* d_out, int out_size, void* d_ws, size_t ws_size,
                              hipStream_t stream) {
    const float* x        = (const float*)d_in[0];
    const float* w1       = (const float*)d_in[1];
    const float* b1       = (const float*)d_in[2];
    const float* ln_g     = (const float*)d_in[3];
    const float* ln_b     = (const float*)d_in[4];
    const float* in_proj  = (const float*)d_in[5];
    const float* cw_f     = (const float*)d_in[6];
    const float* cb_f     = (const float*)d_in[7];
    const float* xp_f     = (const float*)d_in[8];
    const float* dtw_f    = (const float*)d_in[9];
    const float* dtb_f    = (const float*)d_in[10];
    const float* Al_f     = (const float*)d_in[11];
    const float* Dp_f     = (const float*)d_in[12];
    const float* cw_b     = (const float*)d_in[13];
    const float* cb_b     = (const float*)d_in[14];
    const float* xp_b     = (const float*)d_in[15];
    const float* dtw_b    = (const float*)d_in[16];
    const float* dtb_b    = (const float*)d_in[17];
    const float* Al_b     = (const float*)d_in[18];
    const float* Dp_b     = (const float*)d_in[19];
    const float* norm_g   = (const float*)d_in[20];
    const float* norm_b   = (const float*)d_in[21];
    const float* Wout     = (const float*)d_in[22];
    const float* w2       = (const float*)d_in[23];
    const float* b2       = (const float*)d_in[24];

    kmax<<<NROWS * NCHUNK, 256, 0, stream>>>(x);
    kbranch<<<B_SZ * 2, 256, 0, stream>>>(w1, b1, ln_g, ln_b, in_proj,
                                          cw_f, cb_f, xp_f, dtw_f, dtb_f, Al_f, Dp_f,
                                          cw_b, cb_b, xp_b, dtw_b, dtb_b, Al_b, Dp_b);
    kfinal<<<B_SZ, 128, 0, stream>>>(w1, b1, ln_g, ln_b, in_proj,
                                     norm_g, norm_b, Wout, w2, b2, (float*)d_out);
}